// Round 1
// baseline (1249.068 us; speedup 1.0000x reference)
//
#include <hip/hip_runtime.h>
#include <math.h>

// Problem constants (fixed by setup_inputs): b=2,h=16 -> BH=32, L=4096, d=128, chunk=32
#define BH   32
#define LSEQ 4096
#define DK   128
#define DV   128
#define CH   32
#define NC   (LSEQ/CH)     // 128 chunks per head
#define DVG  16            // dv columns per scan block
#define NG   (DV/DVG)      // 8 groups
#define LPAD 132           // padded LDS row stride for 128-wide tiles (bank-conflict-free, 16B aligned)

typedef float4 f4;

__device__ __forceinline__ float dot4(const f4 a, const f4 b) {
    return a.x*b.x + a.y*b.y + a.z*b.z + a.w*b.w;
}

// ---------------------------------------------------------------------------
// Phase 1: per-(head,chunk) preprocessing.
//   qn = l2norm(q), kn = l2norm(k)       (written back in place)
//   T  = forward-subst inverse of (I - strict_tril(k_beta @ kn^T))
//   u  = T @ (v*beta)   -> overwrites v
//   w  = T @ (kn*beta)  -> ws
//   A  = tril_incl(qn @ kn^T)            -> ws (after w)
// grid = BH*NC = 4096 blocks, 256 threads
// ---------------------------------------------------------------------------
__global__ __launch_bounds__(256) void prep_kernel(
    float* __restrict__ q, float* __restrict__ k, float* __restrict__ v,
    const float* __restrict__ beta, float* __restrict__ w, float* __restrict__ Aout)
{
    __shared__ float ks[CH][LPAD];   // normalized k
    __shared__ float kb[CH][LPAD];   // k_beta
    __shared__ float qv[CH][LPAD];   // first qn, later v*beta
    __shared__ float T[CH][CH+1];
    __shared__ float redq[CH][8];
    __shared__ float redk[CH][8];
    __shared__ float bet[CH];
    __shared__ float scq[CH], sck[CH];

    const int tid = threadIdx.x;
    const int hh  = blockIdx.x >> 7;     // / NC
    const int c   = blockIdx.x & (NC-1);
    const size_t rowbase = (size_t)hh * LSEQ + (size_t)c * CH;
    const size_t base    = rowbase * DK;

    const int r   = tid >> 3;     // 0..31 row within chunk
    const int sub = tid & 7;      // 8 threads per row, 16 elems each
    const int d0  = sub * 16;

    // ---- load q,k rows; row sum-of-squares ----
    f4 tq[4], tk[4];
    float sq = 0.f, sk = 0.f;
#pragma unroll
    for (int m = 0; m < 4; ++m) {
        tq[m] = *(const f4*)(q + base + (size_t)r*DK + d0 + m*4);
        tk[m] = *(const f4*)(k + base + (size_t)r*DK + d0 + m*4);
        sq += dot4(tq[m], tq[m]);
        sk += dot4(tk[m], tk[m]);
    }
    redq[r][sub] = sq;
    redk[r][sub] = sk;
    if (tid < CH) bet[tid] = beta[rowbase + tid];
    __syncthreads();
    if (tid < CH) {
        float a = 0.f, b = 0.f;
        for (int j = 0; j < 8; ++j) { a += redq[tid][j]; b += redk[tid][j]; }
        scq[tid] = 1.0f / sqrtf(a + 1e-6f);
        sck[tid] = 1.0f / sqrtf(b + 1e-6f);
    }
    __syncthreads();
    const float aq = scq[r], ak = sck[r], bb = bet[r];
#pragma unroll
    for (int m = 0; m < 4; ++m) {
        tq[m].x *= aq; tq[m].y *= aq; tq[m].z *= aq; tq[m].w *= aq;
        tk[m].x *= ak; tk[m].y *= ak; tk[m].z *= ak; tk[m].w *= ak;
        *(f4*)&qv[r][d0 + m*4] = tq[m];
        *(f4*)&ks[r][d0 + m*4] = tk[m];
        f4 kbv; kbv.x = tk[m].x*bb; kbv.y = tk[m].y*bb; kbv.z = tk[m].z*bb; kbv.w = tk[m].w*bb;
        *(f4*)&kb[r][d0 + m*4] = kbv;
        // store normalized q,k back to global (in place)
        *(f4*)(q + base + (size_t)r*DK + d0 + m*4) = tq[m];
        *(f4*)(k + base + (size_t)r*DK + d0 + m*4) = tk[m];
    }
    __syncthreads();

    // ---- A = tril_incl(qn kn^T) -> global ; T = -(strict tril)(kb kn^T) ----
    {
        const int i = r;
        float av[4];
#pragma unroll
        for (int m = 0; m < 4; ++m) {
            const int j = sub*4 + m;
            float accA = 0.f, accT = 0.f;
            if (j <= i) {
                const f4* x  = (const f4*)qv[i];
                const f4* kp = (const f4*)kb[i];
                const f4* y  = (const f4*)ks[j];
                for (int t = 0; t < 32; ++t) {
                    f4 yy = y[t];
                    accA += dot4(x[t],  yy);
                    accT += dot4(kp[t], yy);
                }
            }
            av[m]   = (j <= i) ? accA : 0.f;
            T[i][j] = (j <  i) ? -accT : 0.f;
        }
        f4 a4; a4.x = av[0]; a4.y = av[1]; a4.z = av[2]; a4.w = av[3];
        *(f4*)(Aout + ((size_t)(hh*NC + c))*(CH*CH) + i*CH + sub*4) = a4;
    }
    __syncthreads();

    // ---- load v, scale by beta, into qv (qn no longer needed in LDS) ----
#pragma unroll
    for (int m = 0; m < 4; ++m) {
        f4 tv = *(const f4*)(v + base + (size_t)r*DK + d0 + m*4);
        tv.x *= bb; tv.y *= bb; tv.z *= bb; tv.w *= bb;
        *(f4*)&qv[r][d0 + m*4] = tv;
    }

    // ---- forward substitution: T <- (I - strict)^{-1} - I pattern ----
    for (int ii = 1; ii < CH; ++ii) {
        float upd = 0.f;
        if (tid < ii) {
            for (int kk = tid + 1; kk < ii; ++kk) upd += T[ii][kk] * T[kk][tid];
        }
        __syncthreads();
        if (tid < ii) T[ii][tid] += upd;
        __syncthreads();
    }
    if (tid < CH) T[tid][tid] = 1.0f;
    __syncthreads();

    // ---- u = T @ vb -> v ; w = T @ kb -> ws ----
    f4 ua[4], wa[4];
#pragma unroll
    for (int m = 0; m < 4; ++m) {
        ua[m].x = ua[m].y = ua[m].z = ua[m].w = 0.f;
        wa[m].x = wa[m].y = wa[m].z = wa[m].w = 0.f;
    }
    for (int j = 0; j <= r; ++j) {
        const float t = T[r][j];
#pragma unroll
        for (int m = 0; m < 4; ++m) {
            f4 vv = *(const f4*)&qv[j][d0 + m*4];
            f4 kk = *(const f4*)&kb[j][d0 + m*4];
            ua[m].x += t*vv.x; ua[m].y += t*vv.y; ua[m].z += t*vv.z; ua[m].w += t*vv.w;
            wa[m].x += t*kk.x; wa[m].y += t*kk.y; wa[m].z += t*kk.z; wa[m].w += t*kk.w;
        }
    }
#pragma unroll
    for (int m = 0; m < 4; ++m) {
        *(f4*)(v + base + (size_t)r*DK + d0 + m*4) = ua[m];
        *(f4*)(w + base + (size_t)r*DK + d0 + m*4) = wa[m];
    }
}

// ---------------------------------------------------------------------------
// Phase 2: sequential chunk scan. One block per (head, dv-group of 16 cols).
//   per chunk: u = u0 - w@S ; o = q@S + A@u ; S += k^T @ u
// grid = NG*BH = 256 blocks, 256 threads.
// blockIdx: hh = bx & 31, g = bx >> 5  (groups of one head land on same XCD
// under round-robin dispatch -> L2 reuse of q/k/w tiles)
// ---------------------------------------------------------------------------
__global__ __launch_bounds__(256) void scan_kernel(
    const float* __restrict__ q, const float* __restrict__ k,
    const float* __restrict__ u0, const float* __restrict__ w,
    const float* __restrict__ A, float* __restrict__ out)
{
    __shared__ float qs[CH][LPAD];
    __shared__ float wsm[CH][LPAD];
    __shared__ float ks[CH][DK];        // column reads -> no pad needed
    __shared__ float S[DK][DVG];
    __shared__ float us[CH][DVG];
    __shared__ float As[CH][36];        // stride 36: pad + 16B aligned

    const int tid = threadIdx.x;
    const int hh  = blockIdx.x & (BH-1);
    const int g   = blockIdx.x >> 5;

    {
        float* Sf = &S[0][0];
        for (int i = tid; i < DK*DVG; i += 256) Sf[i] = 0.f;
    }
    __syncthreads();

    const int r0 = tid >> 4;          // 0..15 (rows r0 and r0+16)
    const int cc = tid & 15;          // dv col within group
    const int du = tid >> 2;          // 0..63 (S rows du, du+64)
    const int cq = (tid & 3) * 4;     // S col quad

    for (int c = 0; c < NC; ++c) {
        const size_t rowbase = (size_t)hh * LSEQ + (size_t)c * CH;
        const size_t base    = rowbase * DK;

        // ---- stage tiles ----
#pragma unroll
        for (int m = 0; m < 4; ++m) {
            int idx = m*256 + tid;          // 0..1023
            int rr  = idx >> 5;
            int dq  = (idx & 31) * 4;
            *(f4*)&qs[rr][dq]  = *(const f4*)(q + base + (size_t)rr*DK + dq);
            *(f4*)&wsm[rr][dq] = *(const f4*)(w + base + (size_t)rr*DK + dq);
            *(f4*)&ks[rr][dq]  = *(const f4*)(k + base + (size_t)rr*DK + dq);
        }
        {
            int rr = tid >> 3, c2 = (tid & 7) * 2;
            *(float2*)&us[rr][c2] =
                *(const float2*)(u0 + base + (size_t)rr*DK + g*DVG + c2);
            int cq4 = (tid & 7) * 4;
            *(f4*)&As[rr][cq4] =
                *(const f4*)(A + ((size_t)(hh*NC + c))*(CH*CH) + rr*CH + cq4);
        }
        __syncthreads();

        // ---- u = u0 - w @ S ----
        float a0 = 0.f, a1 = 0.f;
#pragma unroll 8
        for (int kk = 0; kk < DK; ++kk) {
            float s = S[kk][cc];
            a0 += wsm[r0][kk]    * s;
            a1 += wsm[r0+16][kk] * s;
        }
        float un0 = us[r0][cc]    - a0;
        float un1 = us[r0+16][cc] - a1;
        us[r0][cc]    = un0;
        us[r0+16][cc] = un1;
        __syncthreads();

        // ---- o = q @ S + A @ u ----
        float o0 = 0.f, o1 = 0.f;
#pragma unroll 8
        for (int kk = 0; kk < DK; ++kk) {
            float s = S[kk][cc];
            o0 += qs[r0][kk]    * s;
            o1 += qs[r0+16][kk] * s;
        }
#pragma unroll 8
        for (int j = 0; j < CH; ++j) {
            float uu = us[j][cc];
            o0 += As[r0][j]    * uu;
            o1 += As[r0+16][j] * uu;
        }
        out[base + (size_t)r0*DK      + g*DVG + cc] = o0;
        out[base + (size_t)(r0+16)*DK + g*DVG + cc] = o1;
        __syncthreads();

        // ---- S += k^T @ u ----
        f4 s0 = *(f4*)&S[du][cq];
        f4 s1 = *(f4*)&S[du+64][cq];
#pragma unroll 8
        for (int j = 0; j < CH; ++j) {
            float ka = ks[j][du];
            float kb = ks[j][du+64];
            f4 uu = *(f4*)&us[j][cq];
            s0.x += ka*uu.x; s0.y += ka*uu.y; s0.z += ka*uu.z; s0.w += ka*uu.w;
            s1.x += kb*uu.x; s1.y += kb*uu.y; s1.z += kb*uu.z; s1.w += kb*uu.w;
        }
        *(f4*)&S[du][cq]    = s0;
        *(f4*)&S[du+64][cq] = s1;
        __syncthreads();
    }

    // ---- final state S -> out tail (b,h,dk,dv) ----
    const size_t OUT0 = (size_t)BH * LSEQ * DV;
#pragma unroll
    for (int m = 0; m < 2; ++m) {
        int idx = m*256 + tid;              // 0..511
        int d   = idx >> 2;
        int c4  = (idx & 3) * 4;
        *(f4*)(out + OUT0 + ((size_t)hh*DK + d)*DV + g*DVG + c4) = *(f4*)&S[d][c4];
    }
}

extern "C" void kernel_launch(void* const* d_in, const int* in_sizes, int n_in,
                              void* d_out, int out_size, void* d_ws, size_t ws_size,
                              hipStream_t stream) {
    (void)in_sizes; (void)n_in; (void)out_size; (void)ws_size;
    float* q = (float*)d_in[0];
    float* k = (float*)d_in[1];
    float* v = (float*)d_in[2];
    const float* beta = (const float*)d_in[3];
    float* out = (float*)d_out;

    float* w = (float*)d_ws;                         // BH*LSEQ*DK floats = 64 MB
    float* A = w + (size_t)BH * LSEQ * DK;           // BH*NC*32*32 floats = 16 MB

    prep_kernel<<<dim3(BH*NC), dim3(256), 0, stream>>>(q, k, v, beta, w, A);
    scan_kernel<<<dim3(NG*BH), dim3(256), 0, stream>>>(q, k, v, w, A, out);
}

// Round 2
// 666.654 us; speedup vs baseline: 1.8736x; 1.8736x over previous
//
#include <hip/hip_runtime.h>
#include <math.h>

#define BH   32
#define LSEQ 4096
#define DK   128
#define DV   128
#define CH   32
#define NC   (LSEQ/CH)

typedef float4 f4;
typedef unsigned short u16;
typedef __attribute__((ext_vector_type(8))) short  bf16x8;   // MFMA A/B frag (8 bf16)
typedef __attribute__((ext_vector_type(4))) float  f32x4;    // MFMA C/D frag

#define MFMA16(a,b,c) __builtin_amdgcn_mfma_f32_16x16x32_bf16((a),(b),(c),0,0,0)

__device__ __forceinline__ float dot4(const f4 a, const f4 b) {
    return a.x*b.x + a.y*b.y + a.z*b.z + a.w*b.w;
}
// pack two fp32 -> two bf16 (RNE)
__device__ __forceinline__ unsigned pk2(float a, float b) {
    unsigned ua = __builtin_bit_cast(unsigned, a);
    unsigned ub = __builtin_bit_cast(unsigned, b);
    ua = (ua + 0x7FFFu + ((ua >> 16) & 1u)) >> 16;
    ub = (ub + 0x7FFFu + ((ub >> 16) & 1u)) >> 16;
    return (ua & 0xFFFFu) | (ub << 16);
}

// ---------------------------------------------------------------------------
// Phase 1: per-(head,chunk) prep. fp32 math throughout; emits bf16 operands:
//   qb16[32][128]  = l2norm(q)            (row-major bf16, MFMA A-op ready)
//   wb16[32][128]  = -(T @ k_beta)        (negated! scan does u = u0 + (-w)@S)
//   kT16[128][32]  = l2norm(k)^T          (A-op ready for S += kT@u)
//   A16 [32][32]   = tril_incl(qn kn^T)
//   v  (in place)  = u0 = T @ (v*beta)    (fp32 -> C-frag init in scan)
// grid 4096 x 256
// ---------------------------------------------------------------------------
__global__ __launch_bounds__(256) void prep_kernel(
    const float* __restrict__ q, const float* __restrict__ k, float* __restrict__ v,
    const float* __restrict__ beta,
    u16* __restrict__ qb16, u16* __restrict__ wb16,
    u16* __restrict__ kT16, u16* __restrict__ A16)
{
    __shared__ float ks[CH][132];
    __shared__ float kb[CH][132];
    __shared__ float qv[CH][132];   // qn, later v*beta
    __shared__ float T[CH][CH+1];
    __shared__ float redq[CH][8], redk[CH][8];
    __shared__ float bet[CH], scq[CH], sck[CH];

    const int tid = threadIdx.x;
    const int hh  = blockIdx.x >> 7;
    const int c   = blockIdx.x & (NC-1);
    const size_t rowbase = (size_t)hh * LSEQ + (size_t)c * CH;
    const size_t base    = rowbase * DK;
    const size_t tb      = (size_t)(hh * NC + c);

    const int r = tid >> 3, sub = tid & 7, d0 = sub * 16;

    f4 tq[4], tk[4];
    float sq = 0.f, sk = 0.f;
#pragma unroll
    for (int m = 0; m < 4; ++m) {
        tq[m] = *(const f4*)(q + base + (size_t)r*DK + d0 + m*4);
        tk[m] = *(const f4*)(k + base + (size_t)r*DK + d0 + m*4);
        sq += dot4(tq[m], tq[m]);
        sk += dot4(tk[m], tk[m]);
    }
    redq[r][sub] = sq;
    redk[r][sub] = sk;
    if (tid < CH) bet[tid] = beta[rowbase + tid];
    __syncthreads();
    if (tid < CH) {
        float a = 0.f, b = 0.f;
        for (int j = 0; j < 8; ++j) { a += redq[tid][j]; b += redk[tid][j]; }
        scq[tid] = 1.0f / sqrtf(a + 1e-6f);
        sck[tid] = 1.0f / sqrtf(b + 1e-6f);
    }
    __syncthreads();
    const float aq = scq[r], ak = sck[r], bb = bet[r];
#pragma unroll
    for (int m = 0; m < 4; ++m) {
        tq[m].x *= aq; tq[m].y *= aq; tq[m].z *= aq; tq[m].w *= aq;
        tk[m].x *= ak; tk[m].y *= ak; tk[m].z *= ak; tk[m].w *= ak;
        *(f4*)&qv[r][d0 + m*4] = tq[m];
        *(f4*)&ks[r][d0 + m*4] = tk[m];
        f4 kbv; kbv.x = tk[m].x*bb; kbv.y = tk[m].y*bb; kbv.z = tk[m].z*bb; kbv.w = tk[m].w*bb;
        *(f4*)&kb[r][d0 + m*4] = kbv;
    }
    // qn -> bf16 global (coalesced 32B/thread)
    {
        uint4 p0, p1;
        p0.x = pk2(tq[0].x,tq[0].y); p0.y = pk2(tq[0].z,tq[0].w);
        p0.z = pk2(tq[1].x,tq[1].y); p0.w = pk2(tq[1].z,tq[1].w);
        p1.x = pk2(tq[2].x,tq[2].y); p1.y = pk2(tq[2].z,tq[2].w);
        p1.z = pk2(tq[3].x,tq[3].y); p1.w = pk2(tq[3].z,tq[3].w);
        *(uint4*)(qb16 + tb*4096 + (size_t)r*DK + d0)     = p0;
        *(uint4*)(qb16 + tb*4096 + (size_t)r*DK + d0 + 8) = p1;
    }
    __syncthreads();

    // ---- kT16: transpose kn via LDS, write [128][32] bf16 coalesced ----
    {
        const int d  = tid >> 1;
        const int jh = (tid & 1) * 16;
        unsigned pk[8];
#pragma unroll
        for (int jj = 0; jj < 8; ++jj)
            pk[jj] = pk2(ks[jh + 2*jj][d], ks[jh + 2*jj + 1][d]);
        uint4 a, b2;
        a.x = pk[0]; a.y = pk[1]; a.z = pk[2]; a.w = pk[3];
        b2.x = pk[4]; b2.y = pk[5]; b2.z = pk[6]; b2.w = pk[7];
        *(uint4*)(kT16 + tb*4096 + (size_t)d*32 + jh)     = a;
        *(uint4*)(kT16 + tb*4096 + (size_t)d*32 + jh + 8) = b2;
    }

    // ---- dense A = qn kn^T, Tm = kb kn^T (register-blocked), mask after ----
    {
        const int i = r, j0 = sub * 4;
        float accA[4] = {0,0,0,0}, accT[4] = {0,0,0,0};
        for (int t = 0; t < 32; ++t) {
            f4 xa = *(const f4*)&qv[i][t*4];
            f4 xb = *(const f4*)&kb[i][t*4];
#pragma unroll
            for (int jj = 0; jj < 4; ++jj) {
                f4 y = *(const f4*)&ks[j0+jj][t*4];
                accA[jj] += dot4(xa, y);
                accT[jj] += dot4(xb, y);
            }
        }
#pragma unroll
        for (int jj = 0; jj < 4; ++jj) {
            const int j = j0 + jj;
            accA[jj] = (j <= i) ? accA[jj] : 0.f;
            T[i][j]  = (j <  i) ? -accT[jj] : 0.f;
        }
        uint2 pa; pa.x = pk2(accA[0], accA[1]); pa.y = pk2(accA[2], accA[3]);
        *(uint2*)(A16 + tb*1024 + (size_t)i*32 + j0) = pa;
    }

    // ---- v*beta into qv (safe: row r only read by its own wave above) ----
#pragma unroll
    for (int m = 0; m < 4; ++m) {
        f4 tv = *(const f4*)(v + base + (size_t)r*DK + d0 + m*4);
        tv.x *= bb; tv.y *= bb; tv.z *= bb; tv.w *= bb;
        *(f4*)&qv[r][d0 + m*4] = tv;
    }
    __syncthreads();

    // ---- forward substitution (fp32, serial in i) ----
    for (int ii = 1; ii < CH; ++ii) {
        float upd = 0.f;
        if (tid < ii) {
            for (int kk = tid + 1; kk < ii; ++kk) upd += T[ii][kk] * T[kk][tid];
        }
        __syncthreads();
        if (tid < ii) T[ii][tid] += upd;
        __syncthreads();
    }
    if (tid < CH) T[tid][tid] = 1.0f;
    __syncthreads();

    // ---- u = T @ vb -> v (fp32) ; w = T @ kb -> wb16 (negated bf16) ----
    f4 ua[4], wa[4];
#pragma unroll
    for (int m = 0; m < 4; ++m) {
        ua[m].x = ua[m].y = ua[m].z = ua[m].w = 0.f;
        wa[m].x = wa[m].y = wa[m].z = wa[m].w = 0.f;
    }
    for (int j = 0; j <= r; ++j) {
        const float t = T[r][j];
#pragma unroll
        for (int m = 0; m < 4; ++m) {
            f4 vv = *(const f4*)&qv[j][d0 + m*4];
            f4 kk2 = *(const f4*)&kb[j][d0 + m*4];
            ua[m].x += t*vv.x; ua[m].y += t*vv.y; ua[m].z += t*vv.z; ua[m].w += t*vv.w;
            wa[m].x += t*kk2.x; wa[m].y += t*kk2.y; wa[m].z += t*kk2.z; wa[m].w += t*kk2.w;
        }
    }
#pragma unroll
    for (int m = 0; m < 4; ++m)
        *(f4*)(v + base + (size_t)r*DK + d0 + m*4) = ua[m];
    {
        uint4 p0, p1;
        p0.x = pk2(-wa[0].x,-wa[0].y); p0.y = pk2(-wa[0].z,-wa[0].w);
        p0.z = pk2(-wa[1].x,-wa[1].y); p0.w = pk2(-wa[1].z,-wa[1].w);
        p1.x = pk2(-wa[2].x,-wa[2].y); p1.y = pk2(-wa[2].z,-wa[2].w);
        p1.z = pk2(-wa[3].x,-wa[3].y); p1.w = pk2(-wa[3].z,-wa[3].w);
        *(uint4*)(wb16 + tb*4096 + (size_t)r*DK + d0)     = p0;
        *(uint4*)(wb16 + tb*4096 + (size_t)r*DK + d0 + 8) = p1;
    }
}

// ---------------------------------------------------------------------------
// Phase 2: MFMA scan. One block per (head, 16-wide dv group); 4 waves.
// S (128x16) in fp32 C-frags: wave w owns dk rows [32w,32w+32) as 2 tiles.
// Per chunk:
//   A: waves 0,1: u = u0 + (-w)@S_bf16   (C-init = u0)  -> uT bf16 LDS
//      waves 2,3: Z = q@S_bf16
//   C: waves 2,3: o = Z + A@u -> out ; all: S += kT@u (MFMA, C=S frags)
//      -> ST bf16 LDS for next chunk
// frag layouts (16x16x32 bf16): A[m=lane&15][k=quad*8+j], B[k=quad*8+j][n=lane&15],
//                               D[row=quad*4+reg][col=lane&15]
// ---------------------------------------------------------------------------
__global__ __launch_bounds__(256) void scan_kernel(
    const u16* __restrict__ qb16, const u16* __restrict__ wb16,
    const u16* __restrict__ kT16, const u16* __restrict__ A16,
    const float* __restrict__ u0, float* __restrict__ out)
{
    __shared__ u16 qb[CH][136];     // 272B rows: 16B aligned, bank-rot 4
    __shared__ u16 wb[CH][136];
    __shared__ u16 kT[DK][40];      // 80B rows
    __shared__ u16 Ab[CH][40];
    __shared__ u16 ST[16][136];     // S^T bf16
    __shared__ u16 uT[16][40];      // u^T bf16

    const int tid  = threadIdx.x;
    const int hh   = blockIdx.x & (BH-1);
    const int g    = blockIdx.x >> 5;
    const int wid  = tid >> 6;
    const int lane = tid & 63;
    const int quad = lane >> 4;
    const int m16  = lane & 15;

    for (int i = tid; i < 16*136; i += 256) ((u16*)ST)[i] = 0;
    __syncthreads();

    f32x4 S0 = {0.f,0.f,0.f,0.f}, S1 = {0.f,0.f,0.f,0.f};

    const int srow = tid >> 3, sd0 = (tid & 7) * 16;   // q/w staging
    const int kd = tid >> 1, kjh = (tid & 1) * 16;     // kT staging
    const int aj = (tid & 7) * 4;                      // A staging

    for (int c = 0; c < NC; ++c) {
        const size_t tb = (size_t)(hh * NC + c);
        const u16* qg = qb16 + tb * 4096;
        const u16* wg = wb16 + tb * 4096;
        const u16* kg = kT16 + tb * 4096;
        const u16* Ag = A16  + tb * 1024;

        // ---- stage ----
        {
            uint4 x0 = *(const uint4*)(qg + (size_t)srow*DK + sd0);
            uint4 x1 = *(const uint4*)(qg + (size_t)srow*DK + sd0 + 8);
            uint4 y0 = *(const uint4*)(wg + (size_t)srow*DK + sd0);
            uint4 y1 = *(const uint4*)(wg + (size_t)srow*DK + sd0 + 8);
            uint4 z0 = *(const uint4*)(kg + (size_t)kd*32 + kjh);
            uint4 z1 = *(const uint4*)(kg + (size_t)kd*32 + kjh + 8);
            uint2 za = *(const uint2*)(Ag + (size_t)srow*32 + aj);
            *(uint4*)&qb[srow][sd0]     = x0;  *(uint4*)&qb[srow][sd0+8] = x1;
            *(uint4*)&wb[srow][sd0]     = y0;  *(uint4*)&wb[srow][sd0+8] = y1;
            *(uint4*)&kT[kd][kjh]       = z0;  *(uint4*)&kT[kd][kjh+8]   = z1;
            *(uint2*)&Ab[srow][aj]      = za;
        }
        __syncthreads();

        // ---- phase A ----
        f32x4 acc;
        if (wid < 2) {
            const float* up = u0 + ((size_t)hh*LSEQ + (size_t)c*CH + wid*16 + quad*4)*DK
                                 + g*16 + m16;
            acc.x = up[0]; acc.y = up[DK]; acc.z = up[2*DK]; acc.w = up[3*DK];
#pragma unroll
            for (int ks = 0; ks < 4; ++ks) {
                bf16x8 af = *(const bf16x8*)&wb[wid*16 + m16][ks*32 + quad*8];
                bf16x8 bf = *(const bf16x8*)&ST[m16][ks*32 + quad*8];
                acc = MFMA16(af, bf, acc);
            }
            uint2 p; p.x = pk2(acc.x, acc.y); p.y = pk2(acc.z, acc.w);
            *(uint2*)&uT[m16][wid*16 + quad*4] = p;
        } else {
            acc.x = acc.y = acc.z = acc.w = 0.f;
            const int tile = wid - 2;
#pragma unroll
            for (int ks = 0; ks < 4; ++ks) {
                bf16x8 af = *(const bf16x8*)&qb[tile*16 + m16][ks*32 + quad*8];
                bf16x8 bf = *(const bf16x8*)&ST[m16][ks*32 + quad*8];
                acc = MFMA16(af, bf, acc);
            }
        }
        __syncthreads();

        // ---- phase C ----
        bf16x8 ub = *(const bf16x8*)&uT[m16][quad*8];
        if (wid >= 2) {
            const int tile = wid - 2;
            bf16x8 af = *(const bf16x8*)&Ab[tile*16 + m16][quad*8];
            acc = MFMA16(af, ub, acc);
            float* op = out + ((size_t)hh*LSEQ + (size_t)c*CH + tile*16 + quad*4)*DV
                            + g*16 + m16;
            op[0] = acc.x; op[DV] = acc.y; op[2*DV] = acc.z; op[3*DV] = acc.w;
        }
        {
            bf16x8 a0 = *(const bf16x8*)&kT[wid*32 + m16][quad*8];
            bf16x8 a1 = *(const bf16x8*)&kT[wid*32 + 16 + m16][quad*8];
            S0 = MFMA16(a0, ub, S0);
            S1 = MFMA16(a1, ub, S1);
            uint2 p0; p0.x = pk2(S0.x, S0.y); p0.y = pk2(S0.z, S0.w);
            uint2 p1; p1.x = pk2(S1.x, S1.y); p1.y = pk2(S1.z, S1.w);
            *(uint2*)&ST[m16][wid*32 + quad*4]      = p0;
            *(uint2*)&ST[m16][wid*32 + 16 + quad*4] = p1;
        }
        __syncthreads();
    }

    // ---- final state -> out tail (b,h,dk,dv) fp32 ----
    {
        float* sp = out + (size_t)BH*LSEQ*DV
                        + ((size_t)hh*DK + wid*32 + quad*4)*DV + g*16 + m16;
        sp[0] = S0.x; sp[DV] = S0.y; sp[2*DV] = S0.z; sp[3*DV] = S0.w;
        float* sq = sp + (size_t)16*DV;
        sq[0] = S1.x; sq[DV] = S1.y; sq[2*DV] = S1.z; sq[3*DV] = S1.w;
    }
}

extern "C" void kernel_launch(void* const* d_in, const int* in_sizes, int n_in,
                              void* d_out, int out_size, void* d_ws, size_t ws_size,
                              hipStream_t stream) {
    (void)in_sizes; (void)n_in; (void)out_size; (void)ws_size;
    const float* q = (const float*)d_in[0];
    const float* k = (const float*)d_in[1];
    float* v = (float*)d_in[2];
    const float* beta = (const float*)d_in[3];
    float* out = (float*)d_out;

    const size_t NE = (size_t)BH * LSEQ * DK;          // 16M elems
    u16* qb16 = (u16*)d_ws;                            // 32 MB
    u16* wb16 = qb16 + NE;                             // 32 MB
    u16* kT16 = wb16 + NE;                             // 32 MB
    u16* A16  = kT16 + NE;                             // 8 MB

    prep_kernel<<<dim3(BH*NC), dim3(256), 0, stream>>>(q, k, v, beta, qb16, wb16, kT16, A16);
    scan_kernel<<<dim3(8*BH), dim3(256), 0, stream>>>(qb16, wb16, kT16, A16, v, out);
}

// Round 3
// 389.314 us; speedup vs baseline: 3.2084x; 1.7124x over previous
//
#include <hip/hip_runtime.h>
#include <math.h>

#define BH   32
#define LSEQ 4096
#define DK   128
#define DV   128
#define CH   32
#define NC   (LSEQ/CH)

typedef float4 f4;
typedef unsigned short u16;
typedef __attribute__((ext_vector_type(8))) short  bf16x8;   // MFMA A/B frag (8 bf16)
typedef __attribute__((ext_vector_type(4))) float  f32x4;    // MFMA C/D frag

#define MFMA16(a,b,c) __builtin_amdgcn_mfma_f32_16x16x32_bf16((a),(b),(c),0,0,0)

__device__ __forceinline__ float dot4(const f4 a, const f4 b) {
    return a.x*b.x + a.y*b.y + a.z*b.z + a.w*b.w;
}
__device__ __forceinline__ unsigned pk2(float a, float b) {   // 2x fp32 -> packed bf16 (RNE)
    unsigned ua = __builtin_bit_cast(unsigned, a);
    unsigned ub = __builtin_bit_cast(unsigned, b);
    ua = (ua + 0x7FFFu + ((ua >> 16) & 1u)) >> 16;
    ub = (ub + 0x7FFFu + ((ub >> 16) & 1u)) >> 16;
    return (ua & 0xFFFFu) | (ub << 16);
}
__device__ __forceinline__ u16 bf1(float a) {
    unsigned ua = __builtin_bit_cast(unsigned, a);
    ua = (ua + 0x7FFFu + ((ua >> 16) & 1u)) >> 16;
    return (u16)ua;
}

// ---------------------------------------------------------------------------
// Phase 1 (MFMA prep). Per (head,chunk):
//   qn=l2norm(q) -> qb16 ; kn=l2norm(k) -> kT16 (transposed)
//   A = tril_incl(qn qn... qn kn^T) via MFMA -> A16 (bf16)
//   G = kn kn^T via MFMA ; T = fwd-subst inv of (I - strict_tril(diag(b) G))
//   T' = T diag(b) (bf16) ; u0 = T'@v -> v (fp32) ; w = -(T'@kn) -> wb16
// fwd-subst: single wave, registers + shuffles (no block barriers).
// ---------------------------------------------------------------------------
__global__ __launch_bounds__(256) void prep_kernel(
    const float* __restrict__ q, const float* __restrict__ k, float* __restrict__ v,
    const float* __restrict__ beta,
    u16* __restrict__ qb16, u16* __restrict__ wb16,
    u16* __restrict__ kT16, u16* __restrict__ A16)
{
    __shared__ u16 qn[CH][136];     // bf16 row-major (272B rows, 16B aligned)
    __shared__ u16 kn[CH][136];
    __shared__ u16 vT[DK][40];      // transposed v (no beta), 80B rows
    __shared__ u16 knT[DK][40];     // transposed kn
    __shared__ float Ts[CH][33];    // G -> T -> T'
    __shared__ float Af[CH][33];    // A fp32
    __shared__ u16 Tb[CH][40];      // bf16 T'
    __shared__ float redq[CH][8], redk[CH][8];
    __shared__ float bet[CH], scq[CH], sck[CH];

    const int tid = threadIdx.x;
    const int hh  = blockIdx.x >> 7;
    const int c   = blockIdx.x & (NC-1);
    const size_t rowbase = (size_t)hh * LSEQ + (size_t)c * CH;
    const size_t base    = rowbase * DK;
    const size_t tb      = (size_t)(hh * NC + c);

    const int r = tid >> 3, sub = tid & 7, d0 = sub * 16;
    const int wid = tid >> 6, lane = tid & 63, quad = lane >> 4, m16 = lane & 15;

    // ---- load q,k,v rows; row sum-of-squares ----
    f4 tq[4], tk[4], tv[4];
    float sq = 0.f, sk = 0.f;
#pragma unroll
    for (int m = 0; m < 4; ++m) {
        tq[m] = *(const f4*)(q + base + (size_t)r*DK + d0 + m*4);
        tk[m] = *(const f4*)(k + base + (size_t)r*DK + d0 + m*4);
        tv[m] = *(const f4*)(v + base + (size_t)r*DK + d0 + m*4);
        sq += dot4(tq[m], tq[m]);
        sk += dot4(tk[m], tk[m]);
    }
    redq[r][sub] = sq;
    redk[r][sub] = sk;
    if (tid < CH) bet[tid] = beta[rowbase + tid];
    __syncthreads();
    if (tid < CH) {
        float a = 0.f, b = 0.f;
#pragma unroll
        for (int j = 0; j < 8; ++j) { a += redq[tid][j]; b += redk[tid][j]; }
        scq[tid] = 1.0f / sqrtf(a + 1e-6f);
        sck[tid] = 1.0f / sqrtf(b + 1e-6f);
    }
    __syncthreads();
    const float aq = scq[r], ak = sck[r];
#pragma unroll
    for (int m = 0; m < 4; ++m) {
        tq[m].x *= aq; tq[m].y *= aq; tq[m].z *= aq; tq[m].w *= aq;
        tk[m].x *= ak; tk[m].y *= ak; tk[m].z *= ak; tk[m].w *= ak;
    }
    // qn,kn row-major bf16 LDS + qb16 global
    {
        uint4 p0, p1;
        p0.x = pk2(tq[0].x,tq[0].y); p0.y = pk2(tq[0].z,tq[0].w);
        p0.z = pk2(tq[1].x,tq[1].y); p0.w = pk2(tq[1].z,tq[1].w);
        p1.x = pk2(tq[2].x,tq[2].y); p1.y = pk2(tq[2].z,tq[2].w);
        p1.z = pk2(tq[3].x,tq[3].y); p1.w = pk2(tq[3].z,tq[3].w);
        *(uint4*)&qn[r][d0]     = p0;  *(uint4*)&qn[r][d0+8] = p1;
        *(uint4*)(qb16 + tb*4096 + (size_t)r*DK + d0)     = p0;
        *(uint4*)(qb16 + tb*4096 + (size_t)r*DK + d0 + 8) = p1;
        uint4 k0, k1;
        k0.x = pk2(tk[0].x,tk[0].y); k0.y = pk2(tk[0].z,tk[0].w);
        k0.z = pk2(tk[1].x,tk[1].y); k0.w = pk2(tk[1].z,tk[1].w);
        k1.x = pk2(tk[2].x,tk[2].y); k1.y = pk2(tk[2].z,tk[2].w);
        k1.z = pk2(tk[3].x,tk[3].y); k1.w = pk2(tk[3].z,tk[3].w);
        *(uint4*)&kn[r][d0]     = k0;  *(uint4*)&kn[r][d0+8] = k1;
    }
    // transposed bf16: knT[d][r], vT[d][r]
#pragma unroll
    for (int m = 0; m < 4; ++m) {
        knT[d0+m*4+0][r] = bf1(tk[m].x); knT[d0+m*4+1][r] = bf1(tk[m].y);
        knT[d0+m*4+2][r] = bf1(tk[m].z); knT[d0+m*4+3][r] = bf1(tk[m].w);
        vT [d0+m*4+0][r] = bf1(tv[m].x); vT [d0+m*4+1][r] = bf1(tv[m].y);
        vT [d0+m*4+2][r] = bf1(tv[m].z); vT [d0+m*4+3][r] = bf1(tv[m].w);
    }
    __syncthreads();

    // ---- kT16 global (coalesced) from knT ----
    {
        const int d = tid >> 1, jh = (tid & 1) * 16;
        uint4 z0 = *(const uint4*)&knT[d][jh];
        uint4 z1 = *(const uint4*)&knT[d][jh+8];
        *(uint4*)(kT16 + tb*4096 + (size_t)d*32 + jh)     = z0;
        *(uint4*)(kT16 + tb*4096 + (size_t)d*32 + jh + 8) = z1;
    }
    // ---- MFMA: A = qn kn^T , G = kn kn^T  (wave w -> tile (ti,tj)) ----
    {
        const int ti = wid >> 1, tj = wid & 1;
        f32x4 aA = {0.f,0.f,0.f,0.f}, aG = {0.f,0.f,0.f,0.f};
#pragma unroll
        for (int ks = 0; ks < 4; ++ks) {
            bf16x8 xq = *(const bf16x8*)&qn[ti*16+m16][ks*32 + quad*8];
            bf16x8 xk = *(const bf16x8*)&kn[ti*16+m16][ks*32 + quad*8];
            bf16x8 yk = *(const bf16x8*)&kn[tj*16+m16][ks*32 + quad*8];
            aA = MFMA16(xq, yk, aA);
            aG = MFMA16(xk, yk, aG);
        }
#pragma unroll
        for (int reg = 0; reg < 4; ++reg) {
            Af[ti*16 + quad*4 + reg][tj*16 + m16] = aA[reg];
            Ts[ti*16 + quad*4 + reg][tj*16 + m16] = aG[reg];
        }
    }
    __syncthreads();

    // ---- A16 write (masked) + T init = -strict_tril(diag(b) G) ----
    {
        const int i = r, j0 = sub * 4;
        float a[4];
#pragma unroll
        for (int jj = 0; jj < 4; ++jj)
            a[jj] = (j0+jj <= i) ? Af[i][j0+jj] : 0.f;
        uint2 pa; pa.x = pk2(a[0], a[1]); pa.y = pk2(a[2], a[3]);
        *(uint2*)(A16 + tb*1024 + (size_t)i*32 + j0) = pa;
        const float bi = bet[i];
#pragma unroll
        for (int jj = 0; jj < 4; ++jj) {
            const int j = j0 + jj;
            const float gv = Ts[i][j];
            Ts[i][j] = (j < i) ? -bi * gv : 0.f;
        }
    }
    __syncthreads();

    // ---- forward substitution: wave 0, registers + shuffles ----
    if (tid < 32) {
        float rr[32];
#pragma unroll
        for (int i = 0; i < 32; ++i) rr[i] = Ts[i][tid];
#pragma unroll
        for (int i = 1; i < 32; ++i) {
            float t = 0.f;
#pragma unroll
            for (int kk = 0; kk < i; ++kk)
                t += __shfl(rr[i], kk) * rr[kk];
            rr[i] += t;
        }
        const float bj = bet[tid];
#pragma unroll
        for (int i = 0; i < 32; ++i)
            Ts[i][tid] = ((i == tid) ? 1.0f : rr[i]) * bj;   // T' = T diag(b)
    }
    __syncthreads();
    // ---- pack T' -> bf16 ----
    {
        const int i = r, j0 = sub * 4;
        uint2 p; p.x = pk2(Ts[i][j0], Ts[i][j0+1]); p.y = pk2(Ts[i][j0+2], Ts[i][j0+3]);
        *(uint2*)&Tb[i][j0] = p;
    }
    __syncthreads();

    // ---- u0 = T'@v -> v ; w = -(T'@kn) -> wb16  (transposed orientation) ----
#pragma unroll
    for (int dt = 0; dt < 2; ++dt)
#pragma unroll
    for (int it = 0; it < 2; ++it) {
        const int drow = wid*32 + dt*16 + m16;
        bf16x8 av  = *(const bf16x8*)&vT[drow][quad*8];
        bf16x8 ak2 = *(const bf16x8*)&knT[drow][quad*8];
        bf16x8 bT  = *(const bf16x8*)&Tb[it*16 + m16][quad*8];
        f32x4 aU = {0.f,0.f,0.f,0.f}, aW = {0.f,0.f,0.f,0.f};
        aU = MFMA16(av,  bT, aU);
        aW = MFMA16(ak2, bT, aW);
        const int ii = it*16 + m16;               // chunk row
        const int dd = wid*32 + dt*16 + quad*4;   // feature col base
        f4 us; us.x = aU[0]; us.y = aU[1]; us.z = aU[2]; us.w = aU[3];
        *(f4*)(v + base + (size_t)ii*DK + dd) = us;
        uint2 pw; pw.x = pk2(-aW[0], -aW[1]); pw.y = pk2(-aW[2], -aW[3]);
        *(uint2*)(wb16 + tb*4096 + (size_t)ii*DK + dd) = pw;
    }
}

// ---------------------------------------------------------------------------
// Phase 2: pipelined MFMA scan. 1 block per (head, dv-group of 16); 4 waves.
// Per chunk: 2 barriers. Next chunk's tiles prefetched into registers during
// phase A; qb/wb double-buffered, kT/Ab written in next chunk's A region.
// ---------------------------------------------------------------------------
__global__ __launch_bounds__(256) void scan_kernel(
    const u16* __restrict__ qb16, const u16* __restrict__ wb16,
    const u16* __restrict__ kT16, const u16* __restrict__ A16,
    const float* __restrict__ u0, float* __restrict__ out)
{
    __shared__ u16 qb[2][CH][136];
    __shared__ u16 wb[2][CH][136];
    __shared__ u16 kT[DK][40];
    __shared__ u16 Ab[CH][40];
    __shared__ u16 ST[16][136];     // S^T bf16
    __shared__ u16 uT[16][40];      // u^T bf16

    const int tid  = threadIdx.x;
    const int hh   = blockIdx.x & (BH-1);
    const int g    = blockIdx.x >> 5;
    const int wid  = tid >> 6;
    const int lane = tid & 63;
    const int quad = lane >> 4;
    const int m16  = lane & 15;

    const int srow = tid >> 3, sd0 = (tid & 7) * 16;
    const int kd = tid >> 1, kjh = (tid & 1) * 16;
    const int aj = (tid & 7) * 4;

    for (int i = tid; i < 16*136; i += 256) ((u16*)ST)[i] = 0;

    f32x4 S0 = {0.f,0.f,0.f,0.f}, S1 = {0.f,0.f,0.f,0.f};

    // ---- prefetch chunk 0 ----
    uint4 pq0, pq1, pw0, pw1, pk0, pk1; uint2 pa;
    float pu0 = 0.f, pu1 = 0.f, pu2 = 0.f, pu3 = 0.f;
    {
        const size_t tb = (size_t)(hh * NC);
        const u16* qg = qb16 + tb*4096;
        const u16* wg = wb16 + tb*4096;
        const u16* kg = kT16 + tb*4096;
        const u16* Ag = A16  + tb*1024;
        pq0 = *(const uint4*)(qg + (size_t)srow*DK + sd0);
        pq1 = *(const uint4*)(qg + (size_t)srow*DK + sd0 + 8);
        pw0 = *(const uint4*)(wg + (size_t)srow*DK + sd0);
        pw1 = *(const uint4*)(wg + (size_t)srow*DK + sd0 + 8);
        pk0 = *(const uint4*)(kg + (size_t)kd*32 + kjh);
        pk1 = *(const uint4*)(kg + (size_t)kd*32 + kjh + 8);
        pa  = *(const uint2*)(Ag + (size_t)srow*32 + aj);
        if (wid < 2) {
            const float* up = u0 + ((size_t)hh*LSEQ + wid*16 + quad*4)*DK + g*16 + m16;
            pu0 = up[0]; pu1 = up[DK]; pu2 = up[2*DK]; pu3 = up[3*DK];
        }
    }
    __syncthreads();

    for (int c = 0; c < NC; ++c) {
        const int buf = c & 1;
        // stage q/w for chunk c (regs prefetched one chunk ago)
        *(uint4*)&qb[buf][srow][sd0]   = pq0;  *(uint4*)&qb[buf][srow][sd0+8] = pq1;
        *(uint4*)&wb[buf][srow][sd0]   = pw0;  *(uint4*)&wb[buf][srow][sd0+8] = pw1;
        __syncthreads();                                   // B1
        // stage kT/Ab for chunk c (read only after B2, in phase C)
        *(uint4*)&kT[kd][kjh]  = pk0;  *(uint4*)&kT[kd][kjh+8] = pk1;
        *(uint2*)&Ab[srow][aj] = pa;

        f32x4 acc;
        if (wid < 2) { acc.x = pu0; acc.y = pu1; acc.z = pu2; acc.w = pu3; }
        else         { acc.x = 0.f; acc.y = 0.f; acc.z = 0.f; acc.w = 0.f; }

        // ---- prefetch chunk c+1 ----
        if (c + 1 < NC) {
            const size_t tb = (size_t)(hh*NC + c + 1);
            const u16* qg = qb16 + tb*4096;
            const u16* wg = wb16 + tb*4096;
            const u16* kg = kT16 + tb*4096;
            const u16* Ag = A16  + tb*1024;
            pq0 = *(const uint4*)(qg + (size_t)srow*DK + sd0);
            pq1 = *(const uint4*)(qg + (size_t)srow*DK + sd0 + 8);
            pw0 = *(const uint4*)(wg + (size_t)srow*DK + sd0);
            pw1 = *(const uint4*)(wg + (size_t)srow*DK + sd0 + 8);
            pk0 = *(const uint4*)(kg + (size_t)kd*32 + kjh);
            pk1 = *(const uint4*)(kg + (size_t)kd*32 + kjh + 8);
            pa  = *(const uint2*)(Ag + (size_t)srow*32 + aj);
            if (wid < 2) {
                const float* up = u0 + ((size_t)hh*LSEQ + (size_t)(c+1)*CH + wid*16 + quad*4)*DK
                                     + g*16 + m16;
                pu0 = up[0]; pu1 = up[DK]; pu2 = up[2*DK]; pu3 = up[3*DK];
            }
        }

        // ---- phase A: waves 0/1: u = u0 + (-w)@S ; waves 2/3: Z = q@S ----
        if (wid < 2) {
#pragma unroll
            for (int ks = 0; ks < 4; ++ks) {
                bf16x8 af = *(const bf16x8*)&wb[buf][wid*16 + m16][ks*32 + quad*8];
                bf16x8 bf = *(const bf16x8*)&ST[m16][ks*32 + quad*8];
                acc = MFMA16(af, bf, acc);
            }
            uint2 p; p.x = pk2(acc.x, acc.y); p.y = pk2(acc.z, acc.w);
            *(uint2*)&uT[m16][wid*16 + quad*4] = p;
        } else {
            const int tile = wid - 2;
#pragma unroll
            for (int ks = 0; ks < 4; ++ks) {
                bf16x8 af = *(const bf16x8*)&qb[buf][tile*16 + m16][ks*32 + quad*8];
                bf16x8 bf = *(const bf16x8*)&ST[m16][ks*32 + quad*8];
                acc = MFMA16(af, bf, acc);
            }
        }
        __syncthreads();                                   // B2

        // ---- phase C: o = Z + A@u -> out ; S += kT@u ; ST refresh ----
        bf16x8 ub = *(const bf16x8*)&uT[m16][quad*8];
        if (wid >= 2) {
            const int tile = wid - 2;
            bf16x8 af = *(const bf16x8*)&Ab[tile*16 + m16][quad*8];
            acc = MFMA16(af, ub, acc);
            float* op = out + ((size_t)hh*LSEQ + (size_t)c*CH + tile*16 + quad*4)*DV
                            + g*16 + m16;
            op[0] = acc.x; op[DV] = acc.y; op[2*DV] = acc.z; op[3*DV] = acc.w;
        }
        {
            bf16x8 a0 = *(const bf16x8*)&kT[wid*32 + m16][quad*8];
            bf16x8 a1 = *(const bf16x8*)&kT[wid*32 + 16 + m16][quad*8];
            S0 = MFMA16(a0, ub, S0);
            S1 = MFMA16(a1, ub, S1);
            uint2 p0; p0.x = pk2(S0.x, S0.y); p0.y = pk2(S0.z, S0.w);
            uint2 p1; p1.x = pk2(S1.x, S1.y); p1.y = pk2(S1.z, S1.w);
            *(uint2*)&ST[m16][wid*32 + quad*4]      = p0;
            *(uint2*)&ST[m16][wid*32 + 16 + quad*4] = p1;
        }
        __syncthreads();                                   // (next B1 separates)
    }

    // ---- final state -> out tail (b,h,dk,dv) fp32 ----
    {
        float* sp = out + (size_t)BH*LSEQ*DV
                        + ((size_t)hh*DK + wid*32 + quad*4)*DV + g*16 + m16;
        sp[0] = S0.x; sp[DV] = S0.y; sp[2*DV] = S0.z; sp[3*DV] = S0.w;
        float* sq = sp + (size_t)16*DV;
        sq[0] = S1.x; sq[DV] = S1.y; sq[2*DV] = S1.z; sq[3*DV] = S1.w;
    }
}

extern "C" void kernel_launch(void* const* d_in, const int* in_sizes, int n_in,
                              void* d_out, int out_size, void* d_ws, size_t ws_size,
                              hipStream_t stream) {
    (void)in_sizes; (void)n_in; (void)out_size; (void)ws_size;
    const float* q = (const float*)d_in[0];
    const float* k = (const float*)d_in[1];
    float* v = (float*)d_in[2];
    const float* beta = (const float*)d_in[3];
    float* out = (float*)d_out;

    const size_t NE = (size_t)BH * LSEQ * DK;
    u16* qb16 = (u16*)d_ws;
    u16* wb16 = qb16 + NE;
    u16* kT16 = wb16 + NE;
    u16* A16  = kT16 + NE;

    prep_kernel<<<dim3(BH*NC), dim3(256), 0, stream>>>(q, k, v, beta, qb16, wb16, kT16, A16);
    scan_kernel<<<dim3(8*BH), dim3(256), 0, stream>>>(qb16, wb16, kT16, A16, v, out);
}